// Round 1
// baseline (34.759 us; speedup 1.0000x reference)
//
#include <hip/hip_runtime.h>
#include <hip/hip_bf16.h>

// ARD kernel matrix: out[i][j] = exp(-0.5 * sum_d (x[i][d]-y[j][d])^2 / exp(lbw[d]))
// Quadratic expansion: weight rows by exp(-0.5*lbw), cast to bf16, MFMA GEMM for
// cross term, fused epilogue exp(-0.5*(x2+y2-2*cross)).

typedef __attribute__((ext_vector_type(8))) short bf16x8;   // 8 bf16 = 4 VGPRs
typedef __attribute__((ext_vector_type(4))) float f32x4;    // MFMA accumulator

#define NN 4096
#define MM 4096
#define DD 256

#define BM 128
#define BN 128
#define BK 32
#define NKT (DD / BK)   // 8 K-steps

#define GLOAD16(gp, lp)                                                        \
    __builtin_amdgcn_global_load_lds(                                          \
        (const __attribute__((address_space(1))) void*)(gp),                   \
        (__attribute__((address_space(3))) void*)(lp), 16, 0, 0)

// ---------------------------------------------------------------------------
// prep: one wave per row (x rows then y rows). Scale by exp(-0.5*lbw), cast
// bf16, accumulate row norm from the ROUNDED values (keeps pdist >= 0).
// ---------------------------------------------------------------------------
__global__ __launch_bounds__(256) void ard_prep(
    const float* __restrict__ x, const float* __restrict__ y,
    const float* __restrict__ lbw,
    __hip_bfloat16* __restrict__ xw, __hip_bfloat16* __restrict__ yw,
    float* __restrict__ x2, float* __restrict__ y2)
{
    const int lane = threadIdx.x & 63;
    const int row  = blockIdx.x * 4 + (threadIdx.x >> 6);   // 0 .. N+M-1

    const float* src;
    __hip_bfloat16* dst;
    float* nrm;
    if (row < NN) {
        src = x + (size_t)row * DD;
        dst = xw + (size_t)row * DD;
        nrm = x2 + row;
    } else {
        const int r = row - NN;
        src = y + (size_t)r * DD;
        dst = yw + (size_t)r * DD;
        nrm = y2 + r;
    }

    // 64 lanes x 4 floats = 256 = D
    const float4 v  = reinterpret_cast<const float4*>(src)[lane];
    const float4 lw = reinterpret_cast<const float4*>(lbw)[lane];

    float wv[4];
    wv[0] = v.x * __expf(-0.5f * lw.x);
    wv[1] = v.y * __expf(-0.5f * lw.y);
    wv[2] = v.z * __expf(-0.5f * lw.z);
    wv[3] = v.w * __expf(-0.5f * lw.w);

    __hip_bfloat16 h[4];
    float s = 0.0f;
#pragma unroll
    for (int j = 0; j < 4; ++j) {
        h[j] = __float2bfloat16(wv[j]);
        const float f = __bfloat162float(h[j]);
        s += f * f;
    }

    // vectorized 8B store of 4 bf16
    reinterpret_cast<uint2*>(dst)[lane] = *reinterpret_cast<uint2*>(h);

    // wave-64 reduction
#pragma unroll
    for (int off = 32; off > 0; off >>= 1) s += __shfl_down(s, off);
    if (lane == 0) *nrm = s;
}

// ---------------------------------------------------------------------------
// GEMM + fused epilogue. 128x128 tile, BK=32, 4 waves in 2x2, each wave owns
// a 64x64 sub-tile as 4x4 fragments of mfma_f32_16x16x32_bf16.
// Both operands are row-major [row][K] (cross = xw @ yw^T), so A and B
// fragments load identically: lane reads 16B at s[base + (lane&15)][(lane>>4)*8].
// ---------------------------------------------------------------------------
__global__ __launch_bounds__(256) void ard_gemm(
    const __hip_bfloat16* __restrict__ A,   // xw [N][D]
    const __hip_bfloat16* __restrict__ B,   // yw [M][D]
    const float* __restrict__ x2, const float* __restrict__ y2,
    float* __restrict__ out)                // [N][M]
{
    __shared__ __align__(16) __hip_bfloat16 sA[2][BM][BK];  // 16 KB
    __shared__ __align__(16) __hip_bfloat16 sB[2][BN][BK];  // 16 KB

    const int tid  = threadIdx.x;
    const int lane = tid & 63;
    const int wid  = tid >> 6;     // 0..3
    const int wr   = wid >> 1;     // wave row 0..1
    const int wc   = wid & 1;      // wave col 0..1

    const int bi = blockIdx.y;     // output row tile
    const int bj = blockIdx.x;     // output col tile
    const size_t arow0 = (size_t)bi * BM;
    const size_t brow0 = (size_t)bj * BN;

    // staging geometry: wave `wid` stages rows [wid*32, wid*32+32) of each
    // tile via 2 global_load_lds of 1KB (16 rows x 64B each).
    const int srow = lane >> 2;          // 0..15 within 16-row chunk
    const int scol = (lane & 3) * 8;     // bf16 col offset (16B chunks)

    auto stage = [&](int buf, int kt) {
        const int k0 = kt * BK;
        const int rb = wid * 32;
#pragma unroll
        for (int t = 0; t < 2; ++t) {
            const int r = rb + t * 16 + srow;
            GLOAD16(A + (arow0 + r) * DD + k0 + scol, &sA[buf][rb + t * 16][0]);
            GLOAD16(B + (brow0 + r) * DD + k0 + scol, &sB[buf][rb + t * 16][0]);
        }
    };

    f32x4 acc[4][4] = {};

    stage(0, 0);
    __syncthreads();   // drains vmcnt: buf0 ready

    const int frow = lane & 15;          // fragment row within 16
    const int fk   = (lane >> 4) * 8;    // K sub-offset

#pragma unroll
    for (int kt = 0; kt < NKT; ++kt) {
        const int cur = kt & 1;
        if (kt + 1 < NKT) stage(cur ^ 1, kt + 1);

        bf16x8 a[4], b[4];
#pragma unroll
        for (int m = 0; m < 4; ++m)
            a[m] = *reinterpret_cast<const bf16x8*>(&sA[cur][wr * 64 + m * 16 + frow][fk]);
#pragma unroll
        for (int n = 0; n < 4; ++n)
            b[n] = *reinterpret_cast<const bf16x8*>(&sB[cur][wc * 64 + n * 16 + frow][fk]);

#pragma unroll
        for (int m = 0; m < 4; ++m)
#pragma unroll
            for (int n = 0; n < 4; ++n)
                acc[m][n] = __builtin_amdgcn_mfma_f32_16x16x32_bf16(
                    a[m], b[n], acc[m][n], 0, 0, 0);

        __syncthreads();   // staging of next buf complete; cur consumed
    }

    // epilogue: C/D layout col = lane&15, row = (lane>>4)*4 + reg
    const int row0 = bi * BM + wr * 64;
    const int col0 = bj * BN + wc * 64;
    const int cl   = lane & 15;
    const int rsub = (lane >> 4) * 4;

#pragma unroll
    for (int m = 0; m < 4; ++m) {
        const int rbase = row0 + m * 16 + rsub;
        float xv[4];
#pragma unroll
        for (int j = 0; j < 4; ++j) xv[j] = x2[rbase + j];
#pragma unroll
        for (int n = 0; n < 4; ++n) {
            const int c  = col0 + n * 16 + cl;
            const float yv = y2[c];
#pragma unroll
            for (int j = 0; j < 4; ++j) {
                float t = xv[j] + yv - 2.0f * acc[m][n][j];
                t = fmaxf(t, 0.0f);
                out[(size_t)(rbase + j) * MM + c] = __expf(-0.5f * t);
            }
        }
    }
}

extern "C" void kernel_launch(void* const* d_in, const int* in_sizes, int n_in,
                              void* d_out, int out_size, void* d_ws, size_t ws_size,
                              hipStream_t stream) {
    const float* x   = (const float*)d_in[0];
    const float* y   = (const float*)d_in[1];
    const float* lbw = (const float*)d_in[2];
    float* out = (float*)d_out;

    char* ws = (char*)d_ws;
    __hip_bfloat16* xw = (__hip_bfloat16*)ws;                          // 2 MB
    __hip_bfloat16* yw = (__hip_bfloat16*)(ws + (size_t)2 * 1024 * 1024); // 2 MB
    float* x2 = (float*)(ws + (size_t)4 * 1024 * 1024);                // 16 KB
    float* y2 = (float*)(ws + (size_t)4 * 1024 * 1024 + 16384);        // 16 KB

    // prep: (N+M) rows, 4 rows (waves) per 256-thread block
    ard_prep<<<(NN + MM) / 4, 256, 0, stream>>>(x, y, lbw, xw, yw, x2, y2);

    // gemm: 32x32 tiles of 128x128
    dim3 grid(MM / BN, NN / BM);
    ard_gemm<<<grid, 256, 0, stream>>>(xw, yw, x2, y2, out);
}

// Round 2
// 33.427 us; speedup vs baseline: 1.0398x; 1.0398x over previous
//
#include <hip/hip_runtime.h>
#include <hip/hip_bf16.h>

// ARD kernel matrix: out[i][j] = exp(-0.5 * sum_d (x[i][d]-y[j][d])^2 / exp(lbw[d]))
// Quadratic expansion: weight rows by exp(-0.5*lbw), cast bf16, MFMA GEMM for the
// cross term, fused epilogue exp(-0.5*(x2+y2-2*cross)).
//
// Round 2 structure: full-K LDS staging (128 KB, 1 block/CU), ONE barrier per
// block, XOR-swizzled LDS (T2) so ds_read_b128 fragment loads are conflict-free.
// Swizzle is both-sides-or-neither (rule #21): global_load_lds writes linearly,
// so the READ swizzle is applied to the per-lane GLOBAL source address.

typedef __attribute__((ext_vector_type(8))) short bf16x8;   // 8 bf16 = 4 VGPRs
typedef __attribute__((ext_vector_type(4))) float f32x4;    // MFMA accumulator

#define NN 4096
#define MM 4096
#define DD 256

#define BM 128
#define BN 128

#define GLOAD16(gp, lp)                                                        \
    __builtin_amdgcn_global_load_lds(                                          \
        (const __attribute__((address_space(1))) void*)(gp),                   \
        (__attribute__((address_space(3))) void*)(lp), 16, 0, 0)

// ---------------------------------------------------------------------------
// prep: one wave per row (x rows then y rows). Scale by exp(-0.5*lbw), cast
// bf16, accumulate row norm from the ROUNDED values (keeps pdist >= 0).
// ---------------------------------------------------------------------------
__global__ __launch_bounds__(256) void ard_prep(
    const float* __restrict__ x, const float* __restrict__ y,
    const float* __restrict__ lbw,
    __hip_bfloat16* __restrict__ xw, __hip_bfloat16* __restrict__ yw,
    float* __restrict__ x2, float* __restrict__ y2)
{
    const int lane = threadIdx.x & 63;
    const int row  = blockIdx.x * 4 + (threadIdx.x >> 6);   // 0 .. N+M-1

    const float* src;
    __hip_bfloat16* dst;
    float* nrm;
    if (row < NN) {
        src = x + (size_t)row * DD;
        dst = xw + (size_t)row * DD;
        nrm = x2 + row;
    } else {
        const int r = row - NN;
        src = y + (size_t)r * DD;
        dst = yw + (size_t)r * DD;
        nrm = y2 + r;
    }

    // 64 lanes x 4 floats = 256 = D
    const float4 v  = reinterpret_cast<const float4*>(src)[lane];
    const float4 lw = reinterpret_cast<const float4*>(lbw)[lane];

    float wv[4];
    wv[0] = v.x * __expf(-0.5f * lw.x);
    wv[1] = v.y * __expf(-0.5f * lw.y);
    wv[2] = v.z * __expf(-0.5f * lw.z);
    wv[3] = v.w * __expf(-0.5f * lw.w);

    __hip_bfloat16 h[4];
    float s = 0.0f;
#pragma unroll
    for (int j = 0; j < 4; ++j) {
        h[j] = __float2bfloat16(wv[j]);
        const float f = __bfloat162float(h[j]);
        s += f * f;
    }

    reinterpret_cast<uint2*>(dst)[lane] = *reinterpret_cast<uint2*>(h);

#pragma unroll
    for (int off = 32; off > 0; off >>= 1) s += __shfl_down(s, off);
    if (lane == 0) *nrm = s;
}

// ---------------------------------------------------------------------------
// GEMM + fused epilogue. 128x128 tile, FULL K=256 in LDS, 4 waves in 2x2,
// each wave owns a 64x64 sub-tile as 4x4 fragments of mfma_f32_16x16x32_bf16.
//
// LDS layout (each operand): rows of 512 B; logical byte-col c of row r lives
// at phys byte r*512 + (c ^ ((r&7)<<4)). Fragment ds_read_b128: lanes 0-15 hit
// rows 0-15 at a fixed col -> swizzle spreads rows 0-7 over all 32 banks,
// rows 8-15 repeat (2 lanes/bank = free, m136).
// ---------------------------------------------------------------------------
__global__ __launch_bounds__(256) void ard_gemm(
    const __hip_bfloat16* __restrict__ A,   // xw [N][D]
    const __hip_bfloat16* __restrict__ B,   // yw [M][D]
    const float* __restrict__ x2, const float* __restrict__ y2,
    float* __restrict__ out)                // [N][M]
{
    __shared__ __align__(16) __hip_bfloat16 sA[BM * DD];  // 64 KB
    __shared__ __align__(16) __hip_bfloat16 sB[BN * DD];  // 64 KB

    const int tid  = threadIdx.x;
    const int lane = tid & 63;
    const int wid  = tid >> 6;     // 0..3
    const int wr   = wid >> 1;     // wave row 0..1
    const int wc   = wid & 1;      // wave col 0..1

    const int bi = blockIdx.y;
    const int bj = blockIdx.x;
    const size_t arow0 = (size_t)bi * BM;
    const size_t brow0 = (size_t)bj * BN;

    // ---- stage full K: per GLOAD16, 64 lanes write 1 KB = 2 rows of 512 B.
    // lane l -> LDS byte (base + 16*l); row = base_row + (l>>5), slot = l&31.
    // Pre-swizzle the global source so phys slot s holds logical col s^swz.
    const int srow = lane >> 5;          // 0..1
    const int slot = lane & 31;          // 16B slot within row

#pragma unroll
    for (int t = 0; t < 16; ++t) {
        const int r    = wid * 32 + t * 2;               // wave-uniform LDS row
        const int row  = r + srow;                       // per-lane row
        const int lcb  = (slot * 16) ^ ((row & 7) << 4); // logical byte col
        GLOAD16((const char*)(A + (arow0 + row) * DD) + lcb, (char*)sA + r * 512);
        GLOAD16((const char*)(B + (brow0 + row) * DD) + lcb, (char*)sB + r * 512);
    }
    __syncthreads();   // the ONLY barrier: drains vmcnt, both tiles ready

    f32x4 acc[4][4] = {};
    const int frow = lane & 15;            // fragment row within 16
    const int fkb  = (lane >> 4) * 16;     // K byte sub-offset
    const int aswz = (frow & 7) << 4;      // row&7 == frow&7 (row bases %8==0)

#pragma unroll
    for (int kk = 0; kk < 8; ++kk) {       // K-steps of 32
        bf16x8 a[4], b[4];
        const int kb = kk * 64;            // byte col of this K-step
#pragma unroll
        for (int m = 0; m < 4; ++m) {
            const int row = wr * 64 + m * 16 + frow;
            a[m] = *reinterpret_cast<const bf16x8*>(
                (const char*)sA + row * 512 + ((kb + fkb) ^ aswz));
        }
#pragma unroll
        for (int n = 0; n < 4; ++n) {
            const int row = wc * 64 + n * 16 + frow;
            b[n] = *reinterpret_cast<const bf16x8*>(
                (const char*)sB + row * 512 + ((kb + fkb) ^ aswz));
        }
#pragma unroll
        for (int m = 0; m < 4; ++m)
#pragma unroll
            for (int n = 0; n < 4; ++n)
                acc[m][n] = __builtin_amdgcn_mfma_f32_16x16x32_bf16(
                    a[m], b[n], acc[m][n], 0, 0, 0);
    }

    // epilogue: C/D layout col = lane&15, row = (lane>>4)*4 + reg (verified R1)
    const int row0 = bi * BM + wr * 64;
    const int col0 = bj * BN + wc * 64;
    const int cl   = lane & 15;
    const int rsub = (lane >> 4) * 4;

#pragma unroll
    for (int m = 0; m < 4; ++m) {
        const int rbase = row0 + m * 16 + rsub;
        float xv[4];
#pragma unroll
        for (int j = 0; j < 4; ++j) xv[j] = x2[rbase + j];
#pragma unroll
        for (int n = 0; n < 4; ++n) {
            const int c  = col0 + n * 16 + cl;
            const float yv = y2[c];
#pragma unroll
            for (int j = 0; j < 4; ++j) {
                float t = xv[j] + yv - 2.0f * acc[m][n][j];
                t = fmaxf(t, 0.0f);
                out[(size_t)(rbase + j) * MM + c] = __expf(-0.5f * t);
            }
        }
    }
}

extern "C" void kernel_launch(void* const* d_in, const int* in_sizes, int n_in,
                              void* d_out, int out_size, void* d_ws, size_t ws_size,
                              hipStream_t stream) {
    const float* x   = (const float*)d_in[0];
    const float* y   = (const float*)d_in[1];
    const float* lbw = (const float*)d_in[2];
    float* out = (float*)d_out;

    char* ws = (char*)d_ws;
    __hip_bfloat16* xw = (__hip_bfloat16*)ws;                             // 2 MB
    __hip_bfloat16* yw = (__hip_bfloat16*)(ws + (size_t)2 * 1024 * 1024); // 2 MB
    float* x2 = (float*)(ws + (size_t)4 * 1024 * 1024);                   // 16 KB
    float* y2 = (float*)(ws + (size_t)4 * 1024 * 1024 + 16384);           // 16 KB

    ard_prep<<<(NN + MM) / 4, 256, 0, stream>>>(x, y, lbw, xw, yw, x2, y2);

    dim3 grid(MM / BN, NN / BM);
    ard_gemm<<<grid, 256, 0, stream>>>(xw, yw, x2, y2, out);
}